// Round 9
// baseline (329.889 us; speedup 1.0000x reference)
//
#include <hip/hip_runtime.h>
#include <stdint.h>

// GCN x2 layers x2 branches, N=50000, E=800000, C=64.
// Branch-interleaved f16 tables [node][128] (256 B/row); gathers read one
// uint32/lane covering both branches. MFMA 16x16x32 f16 matmuls (W in VGPRs).
// CSR build: histogram + fused scan (dinv folded in) + fill, with the layer-1
// matmul fused into the fill dispatch (independent block ranges).

typedef _Float16 f16;
typedef _Float16 f16x2 __attribute__((ext_vector_type(2)));
typedef _Float16 f16x8 __attribute__((ext_vector_type(8)));
typedef float f32x4 __attribute__((ext_vector_type(4)));

// ---- degree histogram (doubles as CSR cursor after scanC rewrites it) ----
__global__ void deg_count_k(const int* __restrict__ dst, int nE, int* __restrict__ cnt) {
    int i = blockIdx.x * blockDim.x + threadIdx.x;
    if (i < nE) atomicAdd(&cnt[dst[i]], 1);
}

// ---- scanA: per-block (1024 elems) exclusive scan + dinv ----
__global__ __launch_bounds__(256) void scanA_k(const int* __restrict__ cnt, int n,
                                               int* __restrict__ offs, int* __restrict__ bsums,
                                               float* __restrict__ dinv) {
    int tid = threadIdx.x, lane = tid & 63, wid = tid >> 6;
    int base = blockIdx.x * 1024 + tid * 4;
    int v0 = (base + 0 < n) ? cnt[base + 0] : 0;
    int v1 = (base + 1 < n) ? cnt[base + 1] : 0;
    int v2 = (base + 2 < n) ? cnt[base + 2] : 0;
    int v3 = (base + 3 < n) ? cnt[base + 3] : 0;
    if (base + 0 < n) dinv[base + 0] = 1.0f / sqrtf(1.0f + (float)v0);
    if (base + 1 < n) dinv[base + 1] = 1.0f / sqrtf(1.0f + (float)v1);
    if (base + 2 < n) dinv[base + 2] = 1.0f / sqrtf(1.0f + (float)v2);
    if (base + 3 < n) dinv[base + 3] = 1.0f / sqrtf(1.0f + (float)v3);
    int lsum = v0 + v1 + v2 + v3;
    int s = lsum;
#pragma unroll
    for (int off = 1; off < 64; off <<= 1) {
        int t = __shfl_up(s, off);
        if (lane >= off) s += t;
    }
    __shared__ int wt[4];
    if (lane == 63) wt[wid] = s;
    __syncthreads();
    int woff = 0;
    for (int w = 0; w < wid; ++w) woff += wt[w];
    int excl = woff + s - lsum;
    if (base + 0 < n) offs[base + 0] = excl;
    if (base + 1 < n) offs[base + 1] = excl + v0;
    if (base + 2 < n) offs[base + 2] = excl + v0 + v1;
    if (base + 3 < n) offs[base + 3] = excl + v0 + v1 + v2;
    if (tid == 0) bsums[blockIdx.x] = wt[0] + wt[1] + wt[2] + wt[3];
}

// ---- scanC: add block offsets (each block sums bsums[0..b) itself),
//      write CSR cursor and offs[n] ----
__global__ __launch_bounds__(256) void scanC_k(int* __restrict__ offs,
                                               const int* __restrict__ bsums,
                                               int* __restrict__ cur, int n, int nE) {
    int boff = 0;
    for (int b = 0; b < (int)blockIdx.x; ++b) boff += bsums[b];
    int base = blockIdx.x * 1024 + threadIdx.x * 4;
#pragma unroll
    for (int j = 0; j < 4; ++j) {
        int i = base + j;
        if (i < n) {
            int o = offs[i] + boff;
            offs[i] = o;
            cur[i] = o;
        }
    }
    if (blockIdx.x == 0 && threadIdx.x == 0) offs[n] = nE;
}

// ---- fused: CSR fill (blocks [0,nFill)) + layer-1 MFMA matmul (rest) ----
// mm part: per branch, A[:,br*64:+64] = f16(dinv*(X@W1b)), S likewise (X@Web,
// unscaled). 16x16x32 f16 layouts: A[row=l&15][k=(l>>4)*8+j];
// B[k=(l>>4)*8+j][col=l&15]; D[row=(l>>4)*4+j][col=l&15] (m89-verified).
__global__ __launch_bounds__(256) void fillmm_k(
    const int* __restrict__ src, const int* __restrict__ dst, int nE,
    int* __restrict__ cur, int* __restrict__ elist, int nFill,
    const float* __restrict__ X1, const float* __restrict__ X2,
    const float* __restrict__ Wa1, const float* __restrict__ Wa2,
    const float* __restrict__ Wc1, const float* __restrict__ Wc2,
    const float* __restrict__ dinv,
    f16* __restrict__ A, f16* __restrict__ S, int n) {
    if ((int)blockIdx.x < nFill) {
        int e = blockIdx.x * blockDim.x + threadIdx.x;
        if (e < nE) {
            int p = atomicAdd(&cur[dst[e]], 1);
            elist[p] = src[e];
        }
        return;
    }
    const int bid = blockIdx.x - nFill;     // 0..511
    const int branch = bid >> 8;            // 256 blocks per branch
    const int bx = bid & 255;
    const float* X  = branch ? X2 : X1;
    const float* Wa = branch ? Wa2 : Wa1;
    const float* Wc = branch ? Wc2 : Wc1;
    f16* Oa = A + branch * 64;
    f16* Oc = S + branch * 64;

    const int lane = threadIdx.x & 63;
    const int col = lane & 15;
    const int kgrp = lane >> 4;

    f16x8 wa[4][2], wc[4][2];
#pragma unroll
    for (int ct = 0; ct < 4; ++ct)
#pragma unroll
        for (int kk = 0; kk < 2; ++kk) {
#pragma unroll
            for (int j = 0; j < 8; ++j) {
                int widx = (kk * 32 + kgrp * 8 + j) * 64 + ct * 16 + col;
                wa[ct][kk][j] = (f16)Wa[widx];
                wc[ct][kk][j] = (f16)Wc[widx];
            }
        }

    const int wid = bx * 4 + (threadIdx.x >> 6);
    const int nwaves = 256 * 4;
    const int ntiles = (n + 15) >> 4;
    for (int t = wid; t < ntiles; t += nwaves) {
        int arow = t * 16 + col;
        if (arow >= n) arow = n - 1;
        f16x8 af[2];
#pragma unroll
        for (int kk = 0; kk < 2; ++kk) {
            const float4* px = (const float4*)(X + (size_t)arow * 64 + kk * 32 + kgrp * 8);
            float4 u0 = px[0], u1 = px[1];
            af[kk][0] = (f16)u0.x; af[kk][1] = (f16)u0.y;
            af[kk][2] = (f16)u0.z; af[kk][3] = (f16)u0.w;
            af[kk][4] = (f16)u1.x; af[kk][5] = (f16)u1.y;
            af[kk][6] = (f16)u1.z; af[kk][7] = (f16)u1.w;
        }
        f32x4 acca[4], accc[4];
#pragma unroll
        for (int ct = 0; ct < 4; ++ct) {
            acca[ct] = (f32x4)(0.0f);
            accc[ct] = (f32x4)(0.0f);
        }
#pragma unroll
        for (int ct = 0; ct < 4; ++ct)
#pragma unroll
            for (int kk = 0; kk < 2; ++kk) {
                acca[ct] = __builtin_amdgcn_mfma_f32_16x16x32_f16(af[kk], wa[ct][kk], acca[ct], 0, 0, 0);
                accc[ct] = __builtin_amdgcn_mfma_f32_16x16x32_f16(af[kk], wc[ct][kk], accc[ct], 0, 0, 0);
            }
        int rbase = t * 16 + kgrp * 4;
#pragma unroll
        for (int j = 0; j < 4; ++j) {
            int row = rbase + j;
            if (row < n) {
                float d = dinv[row];
#pragma unroll
                for (int ct = 0; ct < 4; ++ct) {
                    Oa[(size_t)row * 128 + ct * 16 + col] = (f16)(d * acca[ct][j]);
                    Oc[(size_t)row * 128 + ct * 16 + col] = (f16)(accc[ct][j]);
                }
            }
        }
    }
}

// ---- layer-2 MFMA matmul (f16 interleaved in/out, per branch) ----
__global__ __launch_bounds__(256) void mm2_k(
    const f16* __restrict__ H,
    const float* __restrict__ Wa1, const float* __restrict__ Wa2,
    const float* __restrict__ dinv, f16* __restrict__ A, int n) {
    const int branch = blockIdx.y;
    const float* Wa = branch ? Wa2 : Wa1;
    const f16* X = H + branch * 64;
    f16* Oa = A + branch * 64;

    const int lane = threadIdx.x & 63;
    const int col = lane & 15;
    const int kgrp = lane >> 4;

    f16x8 wa[4][2];
#pragma unroll
    for (int ct = 0; ct < 4; ++ct)
#pragma unroll
        for (int kk = 0; kk < 2; ++kk) {
#pragma unroll
            for (int j = 0; j < 8; ++j) {
                int widx = (kk * 32 + kgrp * 8 + j) * 64 + ct * 16 + col;
                wa[ct][kk][j] = (f16)Wa[widx];
            }
        }

    const int wid = blockIdx.x * 4 + (threadIdx.x >> 6);
    const int nwaves = gridDim.x * 4;
    const int ntiles = (n + 15) >> 4;
    for (int t = wid; t < ntiles; t += nwaves) {
        int arow = t * 16 + col;
        if (arow >= n) arow = n - 1;
        f16x8 af[2];
#pragma unroll
        for (int kk = 0; kk < 2; ++kk)
            af[kk] = *(const f16x8*)(X + (size_t)arow * 128 + kk * 32 + kgrp * 8);
        f32x4 acca[4];
#pragma unroll
        for (int ct = 0; ct < 4; ++ct) acca[ct] = (f32x4)(0.0f);
#pragma unroll
        for (int ct = 0; ct < 4; ++ct)
#pragma unroll
            for (int kk = 0; kk < 2; ++kk)
                acca[ct] = __builtin_amdgcn_mfma_f32_16x16x32_f16(af[kk], wa[ct][kk], acca[ct], 0, 0, 0);
        int rbase = t * 16 + kgrp * 4;
#pragma unroll
        for (int j = 0; j < 4; ++j) {
            int row = rbase + j;
            if (row < n) {
                float d = dinv[row];
#pragma unroll
                for (int ct = 0; ct < 4; ++ct)
                    Oa[(size_t)row * 128 + ct * 16 + col] = (f16)(d * acca[ct][j]);
            }
        }
    }
}

// ---- layer-1 agg, BOTH branches in one pass over interleaved table ----
__global__ __launch_bounds__(256) void agg1_k(
    const int* __restrict__ offs, const int* __restrict__ elist,
    const uint32_t* __restrict__ Aw, const uint32_t* __restrict__ Sw,
    const float* __restrict__ b1, const float* __restrict__ b1s,
    const float* __restrict__ be, const float* __restrict__ bes,
    const float* __restrict__ dinv, uint32_t* __restrict__ Hw, int n) {
    int node = blockIdx.x * 4 + (threadIdx.x >> 6);
    int lane = threadIdx.x & 63;
    if (node >= n) return;
    int br = lane >> 5;
    int ch0 = (lane & 31) * 2;
    float bb0 = br ? b1s[ch0] : b1[ch0];
    float bb1 = br ? b1s[ch0 + 1] : b1[ch0 + 1];
    float bs0 = br ? bes[ch0] : be[ch0];
    float bs1 = br ? bes[ch0 + 1] : be[ch0 + 1];

    int e0 = offs[node], e1 = offs[node + 1];
    f16x2 selfv = __builtin_bit_cast(f16x2, Aw[(size_t)node * 64 + lane]);
    float acc0 = (float)selfv.x, acc1 = (float)selfv.y;
    int e = e0;
    for (; e + 7 < e1; e += 8) {
        int s0 = elist[e], s1 = elist[e + 1], s2 = elist[e + 2], s3 = elist[e + 3];
        int s4 = elist[e + 4], s5 = elist[e + 5], s6 = elist[e + 6], s7 = elist[e + 7];
        f16x2 v0 = __builtin_bit_cast(f16x2, Aw[(size_t)s0 * 64 + lane]);
        f16x2 v1 = __builtin_bit_cast(f16x2, Aw[(size_t)s1 * 64 + lane]);
        f16x2 v2 = __builtin_bit_cast(f16x2, Aw[(size_t)s2 * 64 + lane]);
        f16x2 v3 = __builtin_bit_cast(f16x2, Aw[(size_t)s3 * 64 + lane]);
        f16x2 v4 = __builtin_bit_cast(f16x2, Aw[(size_t)s4 * 64 + lane]);
        f16x2 v5 = __builtin_bit_cast(f16x2, Aw[(size_t)s5 * 64 + lane]);
        f16x2 v6 = __builtin_bit_cast(f16x2, Aw[(size_t)s6 * 64 + lane]);
        f16x2 v7 = __builtin_bit_cast(f16x2, Aw[(size_t)s7 * 64 + lane]);
        acc0 += (((float)v0.x + (float)v1.x) + ((float)v2.x + (float)v3.x)) +
                (((float)v4.x + (float)v5.x) + ((float)v6.x + (float)v7.x));
        acc1 += (((float)v0.y + (float)v1.y) + ((float)v2.y + (float)v3.y)) +
                (((float)v4.y + (float)v5.y) + ((float)v6.y + (float)v7.y));
    }
    for (; e < e1; ++e) {
        f16x2 v = __builtin_bit_cast(f16x2, Aw[(size_t)elist[e] * 64 + lane]);
        acc0 += (float)v.x;
        acc1 += (float)v.y;
    }
    float d = dinv[node];
    float g0 = fmaxf(d * acc0 + bb0, 0.0f);
    float g1 = fmaxf(d * acc1 + bb1, 0.0f);
    f16x2 sv = __builtin_bit_cast(f16x2, Sw[(size_t)node * 64 + lane]);
    g0 += fmaxf((float)sv.x + bs0, 0.0f);
    g1 += fmaxf((float)sv.y + bs1, 0.0f);
    f16x2 o; o.x = (f16)g0; o.y = (f16)g1;
    Hw[(size_t)node * 64 + lane] = __builtin_bit_cast(uint32_t, o);
}

// ---- layer-2 agg + Wf dot, BOTH branches in one pass ----
__global__ __launch_bounds__(256) void agg2_dot_k(
    const int* __restrict__ offs, const int* __restrict__ elist,
    const uint32_t* __restrict__ Aw, const uint32_t* __restrict__ Hw,
    const float* __restrict__ b2, const float* __restrict__ b2s,
    const float* __restrict__ Wf, const float* __restrict__ dinv,
    float* __restrict__ dot, int n) {
    int node = blockIdx.x * 4 + (threadIdx.x >> 6);
    int lane = threadIdx.x & 63;
    if (node >= n) return;
    int br = lane >> 5;
    int ch0 = (lane & 31) * 2;
    float bb0 = br ? b2s[ch0] : b2[ch0];
    float bb1 = br ? b2s[ch0 + 1] : b2[ch0 + 1];
    float wf0 = Wf[ch0], wf1 = Wf[ch0 + 1];

    int e0 = offs[node], e1 = offs[node + 1];
    f16x2 selfv = __builtin_bit_cast(f16x2, Aw[(size_t)node * 64 + lane]);
    float acc0 = (float)selfv.x, acc1 = (float)selfv.y;
    int e = e0;
    for (; e + 7 < e1; e += 8) {
        int s0 = elist[e], s1 = elist[e + 1], s2 = elist[e + 2], s3 = elist[e + 3];
        int s4 = elist[e + 4], s5 = elist[e + 5], s6 = elist[e + 6], s7 = elist[e + 7];
        f16x2 v0 = __builtin_bit_cast(f16x2, Aw[(size_t)s0 * 64 + lane]);
        f16x2 v1 = __builtin_bit_cast(f16x2, Aw[(size_t)s1 * 64 + lane]);
        f16x2 v2 = __builtin_bit_cast(f16x2, Aw[(size_t)s2 * 64 + lane]);
        f16x2 v3 = __builtin_bit_cast(f16x2, Aw[(size_t)s3 * 64 + lane]);
        f16x2 v4 = __builtin_bit_cast(f16x2, Aw[(size_t)s4 * 64 + lane]);
        f16x2 v5 = __builtin_bit_cast(f16x2, Aw[(size_t)s5 * 64 + lane]);
        f16x2 v6 = __builtin_bit_cast(f16x2, Aw[(size_t)s6 * 64 + lane]);
        f16x2 v7 = __builtin_bit_cast(f16x2, Aw[(size_t)s7 * 64 + lane]);
        acc0 += (((float)v0.x + (float)v1.x) + ((float)v2.x + (float)v3.x)) +
                (((float)v4.x + (float)v5.x) + ((float)v6.x + (float)v7.x));
        acc1 += (((float)v0.y + (float)v1.y) + ((float)v2.y + (float)v3.y)) +
                (((float)v4.y + (float)v5.y) + ((float)v6.y + (float)v7.y));
    }
    for (; e < e1; ++e) {
        f16x2 v = __builtin_bit_cast(f16x2, Aw[(size_t)elist[e] * 64 + lane]);
        acc0 += (float)v.x;
        acc1 += (float)v.y;
    }
    float d = dinv[node];
    f16x2 hv = __builtin_bit_cast(f16x2, Hw[(size_t)node * 64 + lane]);
    float h0 = fmaxf(d * acc0 + bb0, 0.0f) + (float)hv.x;
    float h1 = fmaxf(d * acc1 + bb1, 0.0f) + (float)hv.y;
    float c = h0 * wf0 + h1 * wf1;
#pragma unroll
    for (int off = 32; off > 0; off >>= 1) c += __shfl_down(c, off);
    if (lane == 0) dot[node] = c;
}

// ---- pool: one block per graph over per-node dots (batch sorted) ----
__device__ inline int lower_bound(const int* __restrict__ batch, int n, int g) {
    int lo = 0, hi = n;
    while (lo < hi) {
        int mid = (lo + hi) >> 1;
        if (batch[mid] < g) lo = mid + 1; else hi = mid;
    }
    return lo;
}

__global__ __launch_bounds__(256) void pool_reduce_k(
    const float* __restrict__ dot, const int* __restrict__ batch, int n,
    const float* __restrict__ bf, float* __restrict__ out) {
    int g = blockIdx.x;
    int start = lower_bound(batch, n, g);
    int end = lower_bound(batch, n, g + 1);
    int tid = threadIdx.x, lane = tid & 63, wid = tid >> 6;
    float acc = 0.f;
    for (int i = start + tid; i < end; i += blockDim.x) acc += dot[i];
#pragma unroll
    for (int off = 32; off > 0; off >>= 1) acc += __shfl_down(acc, off);
    __shared__ float part[4];
    if (lane == 0) part[wid] = acc;
    __syncthreads();
    if (tid == 0) {
        float s = part[0] + part[1] + part[2] + part[3];
        float cnt = fmaxf((float)(end - start), 1.0f);
        out[g] = s / cnt + bf[0];
    }
}

static inline char* alignp(char* p, uintptr_t a) {
    return (char*)(((uintptr_t)p + a - 1) & ~(a - 1));
}

extern "C" void kernel_launch(void* const* d_in, const int* in_sizes, int n_in,
                              void* d_out, int out_size, void* d_ws, size_t ws_size,
                              hipStream_t stream) {
    const float* x    = (const float*)d_in[0];
    const float* x_SC = (const float*)d_in[1];
    const float* W1   = (const float*)d_in[2];
    const float* b1   = (const float*)d_in[3];
    const float* W2   = (const float*)d_in[4];
    const float* b2   = (const float*)d_in[5];
    const float* We   = (const float*)d_in[6];
    const float* be   = (const float*)d_in[7];
    const float* W1s  = (const float*)d_in[8];
    const float* b1s  = (const float*)d_in[9];
    const float* W2s  = (const float*)d_in[10];
    const float* b2s  = (const float*)d_in[11];
    const float* Wes  = (const float*)d_in[12];
    const float* bes  = (const float*)d_in[13];
    const float* Wf   = (const float*)d_in[14];
    const float* bf   = (const float*)d_in[15];
    const int* ei     = (const int*)d_in[16];
    const int* batch  = (const int*)d_in[17];

    const int nN = in_sizes[0] / 64;   // 50000
    const int nE = in_sizes[16] / 2;   // 800000
    const int nG = out_size;           // 64
    const int* esrc = ei;
    const int* edst = ei + nE;
    const int nb = (nN + 1023) / 1024;

    // ---- workspace (64B-aligned chunks) ----
    char* p = (char*)d_ws;
    int* cur    = (int*)p;   p = alignp(p + (size_t)nN * sizeof(int), 64);
    int* offs   = (int*)p;   p = alignp(p + (size_t)(nN + 1) * sizeof(int), 64);
    int* elist  = (int*)p;   p = alignp(p + (size_t)nE * sizeof(int), 64);
    int* bsums  = (int*)p;   p = alignp(p + 1024 * sizeof(int), 64);
    float* dinv = (float*)p; p = alignp(p + (size_t)nN * sizeof(float), 64);
    float* dot  = (float*)p; p = alignp(p + (size_t)nN * sizeof(float), 64);
    f16* A = (f16*)p;        p = alignp(p + (size_t)nN * 128 * sizeof(f16), 64);
    f16* S = (f16*)p;        p = alignp(p + (size_t)nN * 128 * sizeof(f16), 64);
    f16* H = (f16*)p;        p = alignp(p + (size_t)nN * 128 * sizeof(f16), 64);

    const int thr = 256;
    const int gEdgeT = (nE + thr - 1) / thr;   // 3125
    const int gNodeW = (nN + 3) / 4;           // 1 wave/node

    // ---- CSR build (+ dinv folded into scanA) ----
    hipMemsetAsync(cur, 0, (size_t)nN * sizeof(int), stream);
    deg_count_k<<<gEdgeT, thr, 0, stream>>>(edst, nE, cur);
    scanA_k<<<nb, thr, 0, stream>>>(cur, nN, offs, bsums, dinv);
    scanC_k<<<nb, thr, 0, stream>>>(offs, bsums, cur, nN, nE);

    // ---- fill + layer-1 matmul fused (independent block ranges) ----
    fillmm_k<<<gEdgeT + 512, thr, 0, stream>>>(
        esrc, edst, nE, cur, elist, gEdgeT,
        x, x_SC, W1, W1s, We, Wes, dinv, A, S, nN);

    // ---- layer 1 agg (both branches) ----
    agg1_k<<<gNodeW, thr, 0, stream>>>(offs, elist, (const uint32_t*)A, (const uint32_t*)S,
                                       b1, b1s, be, bes, dinv, (uint32_t*)H, nN);

    // ---- layer 2 ----
    mm2_k<<<dim3(256, 2), thr, 0, stream>>>(H, W2, W2s, dinv, A, nN);
    agg2_dot_k<<<gNodeW, thr, 0, stream>>>(offs, elist, (const uint32_t*)A, (const uint32_t*)H,
                                           b2, b2s, Wf, dinv, dot, nN);

    // ---- pool ----
    pool_reduce_k<<<nG, thr, 0, stream>>>(dot, batch, nN, bf, (float*)d_out);
}